// Round 1
// 285.281 us; speedup vs baseline: 1.0061x; 1.0061x over previous
//
#include <hip/hip_runtime.h>

#define B_ 8
#define K_ 100000
#define NODES (B_ * K_)
#define C_ 16
#define O_ 16
#define H_ 512
#define W_ 512
#define TSX 32
#define TSY 16
#define NTX (W_ / TSX)          // 16 tile cols
#define NTY (H_ / TSY)          // 32 tile rows
#define NBKT (B_ * NTX * NTY)   // 4096 buckets
#define CAP 512                 // slots/bucket (lambda≈233 incl. halo, >18 sigma)
#define EX (TSX + 2)            // 34
#define EY (TSY + 2)            // 18
#define PLANE (EX * EY)         // 612
#define FB 1000                 // fill_bins blocks (125 per batch; was 256 -> 1 blk/CU latency-exposed)
#define FPB (FB / B_)           // 125
#define FCHUNK (K_ / FPB)       // 800 nodes per fill block
// ws layout: [0..16KB) cursor[4096] | [16KB..+8MiB) ids | [P_OFF..) p[n][16] fp32
#define IDS_OFF 16384
#define P_OFF (IDS_OFF + NBKT * CAP * 4)                 // 8,404,992
#define WS_NEED ((size_t)P_OFF + (size_t)NODES * O_ * 4) // 59,604,992

__device__ __forceinline__ float bf_lo(unsigned int u) {
    union { unsigned int i; float f; } v; v.i = u << 16; return v.f;
}
__device__ __forceinline__ float bf_hi(unsigned int u) {
    union { unsigned int i; float f; } v; v.i = u & 0xffff0000u; return v.f;
}
__device__ __forceinline__ unsigned short f2bf(float f) {
    union { float f; unsigned int u; } v; v.f = f;
    unsigned int u = v.u;
    u += 0x7fffu + ((u >> 16) & 1u);   // round-to-nearest-even
    return (unsigned short)(u >> 16);
}

// Barrier-free dtype probe: each wave checks the same 256 xy words (bf16 xy
// pairs always decode (low half) into [0,512]; fp32 low halves are random
// mantissa -> P(all pass)≈1e-146). Per-wave __ballot gives every wave the
// identical verdict with NO LDS and NO __syncthreads -> frees the LDS byte
// budget (4 blocks/CU in tile_fused) and removes a barrier dependency.
__device__ __forceinline__ int probe_fp32_ballot(const unsigned int* xy) {
    const int lane = threadIdx.x & 63;
    int bad = 0;
    #pragma unroll
    for (int k = 0; k < 4; ++k) {
        float lo = bf_lo(xy[lane + (k << 6)]);
        bad |= !(lo >= 0.0f && lo <= 512.0f);
    }
    return __ballot(bad) != 0ull;
}

__device__ __forceinline__ void decode_xy(const void* xy, int fp32, int n,
                                          int& xs, int& ys)
{
    float x, y;
    if (fp32) { float2 p = ((const float2*)xy)[n]; x = p.x; y = p.y; }
    else { unsigned int u = ((const unsigned int*)xy)[n]; x = bf_lo(u); y = bf_hi(u); }
    xs = min(max((int)rintf(x), 0), W_ - 1);   // rintf == round-half-even == jnp.round
    ys = min(max((int)rintf(y), 0), H_ - 1);
}

// ---------------------------------------------------------------------------
// Pass 1: bin nodes + (PRE) project feat through W_{type} into p[n][16].
// feat read is COALESCED here (streaming), so the latency-bound tile pass
// never touches feat: it gathers p, which is L3-resident (51MB << 256MB).
// Numerically identical to projecting per-visit (same ops, moved earlier).
// ---------------------------------------------------------------------------
template<bool PRE>
__global__ __launch_bounds__(256) void fill_bins(
    const void* __restrict__ feat, const void* __restrict__ xy,
    const int* __restrict__ types,
    const void* __restrict__ w_obj, const void* __restrict__ w_prior,
    int* __restrict__ cursor, int* __restrict__ ids, float* __restrict__ p)
{
    __shared__ int hist[NTX * NTY];          // 2 KB
    __shared__ unsigned int rec[FCHUNK];     // 3.2 KB packed xs|ys|type
    __shared__ float wl[PRE ? 2 * O_ * C_ : 2];

    const int tid = threadIdx.x;
    const int fp32 = probe_fp32_ballot((const unsigned int*)xy);
    for (int j = tid; j < NTX * NTY; j += 256) hist[j] = 0;
    if constexpr (PRE) {
        for (int i = tid; i < 2 * O_ * C_; i += 256) {
            if (fp32) {
                wl[i] = (i < O_ * C_) ? ((const float*)w_obj)[i]
                                      : ((const float*)w_prior)[i - O_ * C_];
            } else {
                unsigned short raw = (i < O_ * C_)
                    ? ((const unsigned short*)w_obj)[i]
                    : ((const unsigned short*)w_prior)[i - O_ * C_];
                union { unsigned int u; float f; } v; v.u = ((unsigned int)raw) << 16;
                wl[i] = v.f;
            }
        }
    }
    __syncthreads();

    const int bb = blockIdx.x / FPB;
    const int local0 = (blockIdx.x % FPB) * FCHUNK;
    const int s = bb * K_ + local0;

    for (int ii = tid; ii < FCHUNK; ii += 256) {
        const int n = s + ii;
        int xs, ys; decode_xy(xy, fp32, n, xs, ys);
        const int t = (types[n] != 0);
        rec[ii] = (unsigned)(xs | (ys << 9) | (t << 18));

        if constexpr (PRE) {
            float f[16];
            if (fp32) {
                const float4* ff = (const float4*)feat + (size_t)n * 4;
                float4 a = ff[0], b2 = ff[1], c = ff[2], d = ff[3];
                f[0]=a.x; f[1]=a.y; f[2]=a.z; f[3]=a.w;
                f[4]=b2.x; f[5]=b2.y; f[6]=b2.z; f[7]=b2.w;
                f[8]=c.x; f[9]=c.y; f[10]=c.z; f[11]=c.w;
                f[12]=d.x; f[13]=d.y; f[14]=d.z; f[15]=d.w;
            } else {
                const uint4* ff = (const uint4*)feat + (size_t)n * 2;
                uint4 A = ff[0], Bv = ff[1];
                f[0]=bf_lo(A.x);  f[1]=bf_hi(A.x);  f[2]=bf_lo(A.y);  f[3]=bf_hi(A.y);
                f[4]=bf_lo(A.z);  f[5]=bf_hi(A.z);  f[6]=bf_lo(A.w);  f[7]=bf_hi(A.w);
                f[8]=bf_lo(Bv.x); f[9]=bf_hi(Bv.x); f[10]=bf_lo(Bv.y); f[11]=bf_hi(Bv.y);
                f[12]=bf_lo(Bv.z); f[13]=bf_hi(Bv.z); f[14]=bf_lo(Bv.w); f[15]=bf_hi(Bv.w);
            }
            const float* wrow = &wl[t * O_ * C_];
            float pv[16];
            #pragma unroll
            for (int o = 0; o < O_; ++o) {
                float acc = 0.f;
                #pragma unroll
                for (int c = 0; c < C_; ++c) acc = fmaf(wrow[o * C_ + c], f[c], acc);
                pv[o] = acc;
            }
            float4* pout = (float4*)(p + (size_t)n * O_);   // coalesced 64B/node
            pout[0] = make_float4(pv[0],  pv[1],  pv[2],  pv[3]);
            pout[1] = make_float4(pv[4],  pv[5],  pv[6],  pv[7]);
            pout[2] = make_float4(pv[8],  pv[9],  pv[10], pv[11]);
            pout[3] = make_float4(pv[12], pv[13], pv[14], pv[15]);
        }

        int xlo = max((xs - 1) >> 5, 0), xhi = min((xs + 1) >> 5, NTX - 1);
        int ylo = max((ys - 1) >> 4, 0), yhi = min((ys + 1) >> 4, NTY - 1);
        for (int tyy = ylo; tyy <= yhi; ++tyy)
            for (int txx = xlo; txx <= xhi; ++txx)
                atomicAdd(&hist[tyy * NTX + txx], 1);
    }
    __syncthreads();

    for (int j = tid; j < NTX * NTY; j += 256) {
        int c = hist[j];
        hist[j] = c ? atomicAdd(&cursor[bb * NTX * NTY + j], c) : 0;  // reserve
    }
    __syncthreads();

    for (int ii = tid; ii < FCHUNK; ii += 256) {
        unsigned r = rec[ii];
        int xs = r & 511, ys = (r >> 9) & 511, t = (r >> 18) & 1;
        int local = local0 + ii;                       // 17 bits (<100000)
        int xlo = max((xs - 1) >> 5, 0), xhi = min((xs + 1) >> 5, NTX - 1);
        int ylo = max((ys - 1) >> 4, 0), yhi = min((ys + 1) >> 4, NTY - 1);
        for (int tyy = ylo; tyy <= yhi; ++tyy)
            for (int txx = xlo; txx <= xhi; ++txx) {
                int bk = tyy * NTX + txx;
                int slot = atomicAdd(&hist[bk], 1);    // base + local index
                if (slot < CAP) {
                    int lx = xs - (txx << 5) + 1;      // [0,33] 6 bits
                    int ly = ys - (tyy << 4) + 1;      // [0,17] 5 bits
                    ids[(bb * NTX * NTY + bk) * CAP + slot] =
                        local | (t << 17) | (lx << 18) | (ly << 24);
                }
            }
    }
}

// ---------------------------------------------------------------------------
// Pass 2 (fused): per 32x16 tile. PRE: gather precomputed p (L3-resident),
// scatter into LDS, 3x3 conv, nontemporal store. LDS = accs only (39.2 KB)
// -> 4 blocks/CU (was 3). cnt<=CAP<=512 so the node phase is straight-line:
// issue ids+payload loads BEFORE the accs zero-fill to overlap miss latency.
// ---------------------------------------------------------------------------
template<bool PRE>
__global__ __launch_bounds__(512) void tile_fused(
    const void* __restrict__ src /* p if PRE else feat */,
    const void* __restrict__ xy,
    const void* __restrict__ w_obj, const void* __restrict__ w_prior,
    const int* __restrict__ cursor, const int* __restrict__ ids,
    void* __restrict__ out)
{
    __shared__ float accs[O_ * PLANE];               // 39,168 B
    __shared__ float wl[PRE ? 2 : 2 * O_ * C_];

    const int tid = threadIdx.x;
    const int tx = blockIdx.x, ty = blockIdx.y, b = blockIdx.z;
    const int bucket = (b * NTY + ty) * NTX + tx;
    int cnt = cursor[bucket];
    if (cnt > CAP) cnt = CAP;
    const int fp32 = probe_fp32_ballot((const unsigned int*)xy);

    // ---- early issue: ids + payload loads, then zero-fill covers latency ----
    float f[16];
    int t = 0, lx = 0, ly = 0;
    const bool active = (tid < cnt);
    if (active) {
        const unsigned pck = (unsigned)ids[bucket * CAP + tid];
        const int local = pck & 0x1FFFF;
        t  = (pck >> 17) & 1;
        lx = (pck >> 18) & 63;
        ly = (pck >> 24) & 31;
        const size_t n = (size_t)b * K_ + local;
        if constexpr (PRE) {
            const float4* pp = (const float4*)src + n * 4;
            float4 a = pp[0], b2 = pp[1], c = pp[2], d = pp[3];
            f[0]=a.x; f[1]=a.y; f[2]=a.z; f[3]=a.w;
            f[4]=b2.x; f[5]=b2.y; f[6]=b2.z; f[7]=b2.w;
            f[8]=c.x; f[9]=c.y; f[10]=c.z; f[11]=c.w;
            f[12]=d.x; f[13]=d.y; f[14]=d.z; f[15]=d.w;
        } else {
            if (fp32) {
                const float4* ff = (const float4*)src + n * 4;
                float4 a = ff[0], b2 = ff[1], c = ff[2], d = ff[3];
                f[0]=a.x; f[1]=a.y; f[2]=a.z; f[3]=a.w;
                f[4]=b2.x; f[5]=b2.y; f[6]=b2.z; f[7]=b2.w;
                f[8]=c.x; f[9]=c.y; f[10]=c.z; f[11]=c.w;
                f[12]=d.x; f[13]=d.y; f[14]=d.z; f[15]=d.w;
            } else {
                const uint4* ff = (const uint4*)src + n * 2;
                uint4 A = ff[0], Bv = ff[1];
                f[0]=bf_lo(A.x);  f[1]=bf_hi(A.x);  f[2]=bf_lo(A.y);  f[3]=bf_hi(A.y);
                f[4]=bf_lo(A.z);  f[5]=bf_hi(A.z);  f[6]=bf_lo(A.w);  f[7]=bf_hi(A.w);
                f[8]=bf_lo(Bv.x); f[9]=bf_hi(Bv.x); f[10]=bf_lo(Bv.y); f[11]=bf_hi(Bv.y);
                f[12]=bf_lo(Bv.z); f[13]=bf_hi(Bv.z); f[14]=bf_lo(Bv.w); f[15]=bf_hi(Bv.w);
            }
        }
    }

    for (int i = tid; i < O_ * PLANE; i += 512) accs[i] = 0.f;
    if constexpr (!PRE) {
        if (fp32) {
            for (int i = tid; i < 2 * O_ * C_; i += 512)
                wl[i] = (i < O_ * C_) ? ((const float*)w_obj)[i]
                                      : ((const float*)w_prior)[i - O_ * C_];
        } else {
            for (int i = tid; i < 2 * O_ * C_; i += 512) {
                unsigned short raw = (i < O_ * C_)
                    ? ((const unsigned short*)w_obj)[i]
                    : ((const unsigned short*)w_prior)[i - O_ * C_];
                union { unsigned int u; float f; } v; v.u = ((unsigned int)raw) << 16;
                wl[i] = v.f;
            }
        }
    }
    __syncthreads();

    if (active) {
        float* cell = &accs[ly * EX + lx];
        if constexpr (PRE) {
            #pragma unroll
            for (int o = 0; o < O_; ++o) atomicAdd(cell + o * PLANE, f[o]);
        } else {
            const float* wrow = &wl[t * O_ * C_];
            #pragma unroll
            for (int o = 0; o < O_; ++o) {
                float acc = 0.f;
                #pragma unroll
                for (int c = 0; c < C_; ++c) acc = fmaf(wrow[o * C_ + c], f[c], acc);
                atomicAdd(cell + o * PLANE, acc);
            }
        }
    }
    __syncthreads();

    // conv: thread = (o = tid>>5, x = tid&31); rolling vertical window.
    const int x = tid & 31;
    const int o = tid >> 5;
    const float* pl = &accs[o * PLANE + x];
    float hA2 = 0.f, hA1 = 0.f, hB1 = 0.f;
    const int x0 = tx * TSX, y0 = ty * TSY;
    const size_t obase = (((size_t)(b * O_ + o)) * H_) * W_;

    #pragma unroll
    for (int iy = 0; iy < EY; ++iy) {
        float l = pl[iy * EX], c = pl[iy * EX + 1], r = pl[iy * EX + 2];
        float sfx = l + r;
        float hA = fmaf(0.075f, sfx, 0.125f * c);
        float hB = fmaf(0.125f, sfx, 0.3f * c);
        if (iy >= 2) {
            float v = hA2 + hB1 + hA;
            size_t oi = obase + (size_t)(y0 + iy - 2) * W_ + (x0 + x);
            if (fp32) __builtin_nontemporal_store(v, (float*)out + oi);
            else      __builtin_nontemporal_store(f2bf(v), (unsigned short*)out + oi);
        }
        hA2 = hA1; hA1 = hA; hB1 = hB;
    }
}

extern "C" void kernel_launch(void* const* d_in, const int* in_sizes, int n_in,
                              void* d_out, int out_size, void* d_ws, size_t ws_size,
                              hipStream_t stream)
{
    const void* feat = d_in[0];                    // [8,100000,16] fp32 (or bf16)
    const void* xy = d_in[1];                      // [8,100000,2]
    // d_in[2] = hw (int64 [2]) -- constants 512x512, unused
    const int* types = (const int*)d_in[3];        // int32 [8,100000]
    const void* w_obj = d_in[4];                   // [16,16]
    const void* w_prior = d_in[5];                 // [16,16]

    int* cursor = (int*)d_ws;
    int* ids = (int*)((char*)d_ws + IDS_OFF);
    float* p = (float*)((char*)d_ws + P_OFF);

    hipMemsetAsync(cursor, 0, NBKT * sizeof(int), stream);
    if (ws_size >= WS_NEED) {
        fill_bins<true><<<FB, 256, 0, stream>>>(feat, xy, types, w_obj, w_prior,
                                                cursor, ids, p);
        tile_fused<true><<<dim3(NTX, NTY, B_), 512, 0, stream>>>(
            p, xy, w_obj, w_prior, cursor, ids, d_out);
    } else {
        // workspace too small for p-buffer: previous (projection-in-tile) path
        fill_bins<false><<<FB, 256, 0, stream>>>(feat, xy, types, w_obj, w_prior,
                                                 cursor, ids, p);
        tile_fused<false><<<dim3(NTX, NTY, B_), 512, 0, stream>>>(
            feat, xy, w_obj, w_prior, cursor, ids, d_out);
    }
}